// Round 4
// baseline (76.521 us; speedup 1.0000x reference)
//
#include <hip/hip_runtime.h>

#define DIM 256
#define L_ 128
#define TD 64
#define NVOCAB 150
#define NB 2048

__device__ __forceinline__ float dot4(float4 a, float4 b) {
    return fmaf(a.x, b.x, fmaf(a.y, b.y, fmaf(a.z, b.z, a.w * b.w)));
}

// ---------------------------------------------------------------------------
// Kernel A: M[c][d] = (1/16) * sum_e Wq[e][c] * Wk[e][d]   (256x256)
//           plus per-vocab scalar tables (BETA=0.5 folded in):
//           rel_s[v] = 0.5 * dot(rel_emb_w[v], Wrp[0:64])
//           pos_s[v] = 0.5 * dot(pos_emb_w[v], Wrp[64:128])
// ---------------------------------------------------------------------------
__global__ __launch_bounds__(256) void prep_kernel(
    const float* __restrict__ Wk, const float* __restrict__ Wq,
    const float* __restrict__ Wrp,
    const float* __restrict__ rel_emb_w, const float* __restrict__ pos_emb_w,
    float* __restrict__ M, float* __restrict__ rel_s, float* __restrict__ pos_s)
{
    if (blockIdx.x == DIM) {
        int v = threadIdx.x;
        if (v < NVOCAB) {
            float sr = 0.f, sp = 0.f;
#pragma unroll 8
            for (int j = 0; j < TD; ++j) {
                sr = fmaf(rel_emb_w[v * TD + j], Wrp[j], sr);
                sp = fmaf(pos_emb_w[v * TD + j], Wrp[TD + j], sp);
            }
            rel_s[v] = 0.5f * sr;
            pos_s[v] = 0.5f * sp;
        }
        return;
    }
    int cc = blockIdx.x;   // uniform per block -> Wq reads become scalar loads
    int d  = threadIdx.x;
    float acc = 0.f;
#pragma unroll 16
    for (int e = 0; e < DIM; ++e)
        acc = fmaf(Wq[e * DIM + cc], Wk[e * DIM + d], acc);
    M[cc * DIM + d] = acc * (1.0f / 16.0f);   // temperature = sqrt(256) = 16
}

// ---------------------------------------------------------------------------
// Kernel B: qk[b][d] = sum_c hn[b][c] * M[c][d]  (hn @ M), 8 rows per block.
// ---------------------------------------------------------------------------
__global__ __launch_bounds__(256) void qk_kernel(
    const float* __restrict__ hn, const float* __restrict__ M,
    float* __restrict__ qk)
{
    __shared__ float hn_s[8][DIM];
    const int r0 = blockIdx.x * 8;
    const int t = threadIdx.x;
#pragma unroll
    for (int i = 0; i < 8; ++i)
        hn_s[i][t] = hn[(size_t)(r0 + i) * DIM + t];
    __syncthreads();
    float acc[8] = {0.f, 0.f, 0.f, 0.f, 0.f, 0.f, 0.f, 0.f};
#pragma unroll 8
    for (int c = 0; c < DIM; ++c) {
        float m = M[c * DIM + t];
#pragma unroll
        for (int r = 0; r < 8; ++r)
            acc[r] = fmaf(hn_s[r][c], m, acc[r]);
    }
#pragma unroll
    for (int r = 0; r < 8; ++r)
        qk[(size_t)(r0 + r) * DIM + t] = acc[r];
}

// ---------------------------------------------------------------------------
// Pass 1: 8192 blocks = (b, h), h = quarter of b's rows (32 rows).
// 256 threads = 16 groups x 16 lanes. Group grp handles rows
// {32h+grp, 32h+grp+16}; lane c holds 16 cols (float4 c+16j, j=0..3).
// Per-group 2-row softmax partial; block merge of 16 groups through LDS;
// unnormalized partial (m, d, o[256]) written to workspace.
// ---------------------------------------------------------------------------
__global__ __launch_bounds__(256, 5) void attn_pass1(
    const float* __restrict__ outp, const float* __restrict__ qk,
    const int* __restrict__ pos_ind, const int* __restrict__ rel_dt,
    const float* __restrict__ rel_s, const float* __restrict__ pos_s,
    float* __restrict__ part_o, float* __restrict__ part_md)
{
    const int pb  = blockIdx.x;         // 0..8191
    const int b   = pb >> 2;
    const int h   = pb & 3;
    const int t   = threadIdx.x;        // 0..255
    const int grp = t >> 4;             // 0..15 (16-lane aligned)
    const int c   = t & 15;

    __shared__ float mG[16];
    __shared__ float dG[16];
    __shared__ float red[16][DIM];

    // ---- issue the 8 data loads first ----
    const float4* __restrict__ src = (const float4*)outp + (size_t)b * (L_ * 64);
    const int r0 = h * 32 + grp;
    float4 v0[4], v1[4];
#pragma unroll
    for (int j = 0; j < 4; ++j) v0[j] = src[(r0     ) * 64 + j * 16 + c];
#pragma unroll
    for (int j = 0; j < 4; ++j) v1[j] = src[(r0 + 16) * 64 + j * 16 + c];

    // qk fragment (L2-hot)
    const float4* __restrict__ qp = (const float4*)qk + (size_t)b * 64;
    float4 q[4];
#pragma unroll
    for (int j = 0; j < 4; ++j) q[j] = qp[j * 16 + c];

    // bias for this group's 2 rows (same addr across the 16 lanes -> broadcast)
    const int pi0 = pos_ind[b * L_ + r0],      rd0 = rel_dt[b * L_ + r0];
    const int pi1 = pos_ind[b * L_ + r0 + 16], rd1 = rel_dt[b * L_ + r0 + 16];
    const float bi0 = (pi0 == 0) ? -1e30f : (rel_s[rd0] + pos_s[pi0]);
    const float bi1 = (pi1 == 0) ? -1e30f : (rel_s[rd1] + pos_s[pi1]);

    // ---- 2 logits, 16-lane allreduce (chains overlap) ----
    float p0 = dot4(v0[0], q[0]) + dot4(v0[1], q[1]) + dot4(v0[2], q[2]) + dot4(v0[3], q[3]);
    float p1 = dot4(v1[0], q[0]) + dot4(v1[1], q[1]) + dot4(v1[2], q[2]) + dot4(v1[3], q[3]);
    p0 += __shfl_xor(p0, 1);  p1 += __shfl_xor(p1, 1);
    p0 += __shfl_xor(p0, 2);  p1 += __shfl_xor(p1, 2);
    p0 += __shfl_xor(p0, 4);  p1 += __shfl_xor(p1, 4);
    p0 += __shfl_xor(p0, 8);  p1 += __shfl_xor(p1, 8);
    const float lg0 = p0 + bi0, lg1 = p1 + bi1;

    const float m  = fmaxf(lg0, lg1);
    const float w0 = __expf(lg0 - m), w1 = __expf(lg1 - m);
    const float d  = w0 + w1;

    // ---- block merge of 16 group states ----
    if (c == 0) { mG[grp] = m; dG[grp] = d; }
    __syncthreads();
    float Mb = mG[0];
#pragma unroll
    for (int g = 1; g < 16; ++g) Mb = fmaxf(Mb, mG[g]);   // LDS broadcasts
    const float f   = __expf(m - Mb);
    const float fw0 = f * w0, fw1 = f * w1;
    if (t == 0) {
        float D = 0.f;
#pragma unroll
        for (int g = 0; g < 16; ++g) D += dG[g] * __expf(mG[g] - Mb);
        part_md[pb * 2]     = Mb;
        part_md[pb * 2 + 1] = D;
    }
    float4* rw = (float4*)(&red[grp][0]);
#pragma unroll
    for (int j = 0; j < 4; ++j) {
        float4 o;
        o.x = fmaf(fw0, v0[j].x, fw1 * v1[j].x);
        o.y = fmaf(fw0, v0[j].y, fw1 * v1[j].y);
        o.z = fmaf(fw0, v0[j].z, fw1 * v1[j].z);
        o.w = fmaf(fw0, v0[j].w, fw1 * v1[j].w);
        rw[j * 16 + c] = o;
    }
    __syncthreads();

    float s = 0.f;
#pragma unroll
    for (int g = 0; g < 16; ++g) s += red[g][t];          // 2-way banked, free
    part_o[(size_t)pb * DIM + t] = s;
}

// ---------------------------------------------------------------------------
// Pass 2: merge the 4 partials of each b.  2048 blocks x 256 threads.
// ---------------------------------------------------------------------------
__global__ __launch_bounds__(256) void attn_pass2(
    const float* __restrict__ part_o, const float* __restrict__ part_md,
    float* __restrict__ y)
{
    const int b = blockIdx.x;
    const int t = threadIdx.x;
    const float m0 = part_md[(b * 4 + 0) * 2], e0 = part_md[(b * 4 + 0) * 2 + 1];
    const float m1 = part_md[(b * 4 + 1) * 2], e1 = part_md[(b * 4 + 1) * 2 + 1];
    const float m2 = part_md[(b * 4 + 2) * 2], e2 = part_md[(b * 4 + 2) * 2 + 1];
    const float m3 = part_md[(b * 4 + 3) * 2], e3 = part_md[(b * 4 + 3) * 2 + 1];
    const float Mx = fmaxf(fmaxf(m0, m1), fmaxf(m2, m3));
    const float w0 = __expf(m0 - Mx), w1 = __expf(m1 - Mx);
    const float w2 = __expf(m2 - Mx), w3 = __expf(m3 - Mx);
    const float D  = e0 * w0 + e1 * w1 + e2 * w2 + e3 * w3;
    float s = part_o[(size_t)(b * 4 + 0) * DIM + t] * w0;
    s = fmaf(part_o[(size_t)(b * 4 + 1) * DIM + t], w1, s);
    s = fmaf(part_o[(size_t)(b * 4 + 2) * DIM + t], w2, s);
    s = fmaf(part_o[(size_t)(b * 4 + 3) * DIM + t], w3, s);
    y[(size_t)b * DIM + t] = s / D;
}

// ---------------------------------------------------------------------------
extern "C" void kernel_launch(void* const* d_in, const int* in_sizes, int n_in,
                              void* d_out, int out_size, void* d_ws, size_t ws_size,
                              hipStream_t stream)
{
    const float* out_t     = (const float*)d_in[0];  // [B, L, DIM]
    const float* hn        = (const float*)d_in[1];  // [B, DIM]
    const int*   pos_ind   = (const int*)  d_in[2];  // [B, L]
    const int*   rel_dt    = (const int*)  d_in[3];  // [B, L]
    // d_in[4] = abs_dt (unused)
    const float* pos_emb_w = (const float*)d_in[5];  // [VOCAB, TD]
    const float* rel_emb_w = (const float*)d_in[6];  // [VOCAB, TD]
    const float* Wk        = (const float*)d_in[7];  // [DIM, DIM]
    const float* Wq        = (const float*)d_in[8];  // [DIM, DIM]
    const float* Wrp       = (const float*)d_in[9];  // [1, 2*TD]

    float* y = (float*)d_out;                        // [B, DIM] fp32

    // ws layout (floats):
    //   M[65536] | qk[NB*DIM] | rel_s[256] | pos_s[256]
    //   | part_o[NB*4*DIM] | part_md[NB*4*2]
    float* M       = (float*)d_ws;
    float* qk      = M + DIM * DIM;
    float* rel_s   = qk + (size_t)NB * DIM;
    float* pos_s   = rel_s + 256;
    float* part_o  = pos_s + 256;
    float* part_md = part_o + (size_t)NB * 4 * DIM;

    prep_kernel<<<DIM + 1, 256, 0, stream>>>(Wk, Wq, Wrp, rel_emb_w, pos_emb_w,
                                             M, rel_s, pos_s);
    qk_kernel<<<NB / 8, 256, 0, stream>>>(hn, M, qk);
    attn_pass1<<<NB * 4, 256, 0, stream>>>(out_t, qk, pos_ind, rel_dt,
                                           rel_s, pos_s, part_o, part_md);
    attn_pass2<<<NB, 256, 0, stream>>>(part_o, part_md, y);
}